// Round 2
// baseline (985.605 us; speedup 1.0000x reference)
//
#include <hip/hip_runtime.h>
#include <math.h>

#define NE 4096
#define NW 8192
#define KK 128
#define GG 1024
#define MM 64
#define JJ 256

#define NB_R   2048            // reduction blocks
#define NB_TOT (NB_R + GG + 1) // + 1024 sim blocks + 1 entity block

// ws layout (floats): 0=recon_ss, 1=w_relu_ss, 2=e_relu_ss, 3=sim_penalty, 4=ticket(uint)

// ---------------------------------------------------------------------------
// Single fused kernel.
//  blocks [0, NB_R):         grid-stride reduction over
//      region 0: sum((actual-prediction)^2) -> acc[0]
//      region 1: sum(relu(W)^2)             -> acc[1]
//      region 2: sum(relu(E)^2)             -> acc[2]
//  blocks [NB_R, NB_R+GG):   word sim term, one block per g -> acc[3]
//  block  NB_R+GG:           entity sim term                -> acc[3]
//  last block to finish (atomic ticket) computes out[0].
// ---------------------------------------------------------------------------
__global__ __launch_bounds__(256) void k_fused(
    const float4* __restrict__ A, const float4* __restrict__ P,
    const float4* __restrict__ W4, const float4* __restrict__ E4,
    const float* __restrict__ W, const float* __restrict__ E,
    const float* __restrict__ Sw, const float* __restrict__ Se,
    const int* __restrict__ row_ind,
    const int* __restrict__ wi, const int* __restrict__ ej,
    const int* __restrict__ sj,
    const float* __restrict__ lamb,
    float* __restrict__ acc, float* __restrict__ out)
{
    __shared__ float lds[3][4];
    __shared__ int wi_s[MM];
    const int b = blockIdx.x;
    const int t = threadIdx.x;
    const int lane = t & 63, wid = t >> 6;

    if (b < NB_R) {
        // ---- big streaming reduction ----
        const size_t RQ = (size_t)NE * NW / 4;
        const size_t WQ = (size_t)KK * NW / 4;
        const size_t EQ = (size_t)NE * KK / 4;
        const size_t TOT = RQ + WQ + EQ;

        float r0 = 0.f, r1 = 0.f, r2 = 0.f;
        const size_t stride = (size_t)NB_R * 256;
        for (size_t i = (size_t)b * 256 + t; i < TOT; i += stride) {
            if (i < RQ) {
                float4 a = A[i];
                float4 p = P[i];
                float dx = a.x - p.x, dy = a.y - p.y, dz = a.z - p.z, dw = a.w - p.w;
                r0 += dx * dx + dy * dy + dz * dz + dw * dw;
            } else if (i < RQ + WQ) {
                float4 w = W4[i - RQ];
                float x = fmaxf(w.x, 0.f), y = fmaxf(w.y, 0.f);
                float z = fmaxf(w.z, 0.f), u = fmaxf(w.w, 0.f);
                r1 += x * x + y * y + z * z + u * u;
            } else {
                float4 e = E4[i - RQ - WQ];
                float x = fmaxf(e.x, 0.f), y = fmaxf(e.y, 0.f);
                float z = fmaxf(e.z, 0.f), u = fmaxf(e.w, 0.f);
                r2 += x * x + y * y + z * z + u * u;
            }
        }
        #pragma unroll
        for (int off = 32; off > 0; off >>= 1) {
            r0 += __shfl_down(r0, off);
            r1 += __shfl_down(r1, off);
            r2 += __shfl_down(r2, off);
        }
        if (lane == 0) { lds[0][wid] = r0; lds[1][wid] = r1; lds[2][wid] = r2; }
        __syncthreads();
        if (t == 0) {
            float s0 = 0.f, s1 = 0.f, s2 = 0.f;
            #pragma unroll
            for (int w = 0; w < 4; ++w) { s0 += lds[0][w]; s1 += lds[1][w]; s2 += lds[2][w]; }
            atomicAdd(acc + 0, s0);
            atomicAdd(acc + 1, s1);
            atomicAdd(acc + 2, s2);
        }
    } else if (b < NB_R + GG) {
        // ---- word sim term, g = b - NB_R ----
        const int g = b - NB_R;
        const int sjv = sj[g];
        if (t < MM) wi_s[t] = wi[g * MM + t];
        __syncthreads();

        const int k = t & 127;       // 2 threads per k
        const int half = t >> 7;     // each covers half the m range
        const float* Wk = W + (size_t)k * NW;
        const float wj = Wk[sjv];
        float a = 0.f;
        #pragma unroll 8
        for (int m = half * 32; m < half * 32 + 32; ++m) {
            float x = Wk[wi_s[m]] - wj;
            a = fmaf(x, x, a);
        }
        float sw = (t < MM) ? Sw[(size_t)sjv * NW + wi_s[t]] : 0.f;

        #pragma unroll
        for (int off = 32; off > 0; off >>= 1) {
            a += __shfl_down(a, off);
            sw += __shfl_down(sw, off);
        }
        if (lane == 0) { lds[0][wid] = a; lds[1][wid] = sw; }
        __syncthreads();
        if (t == 0) {
            float at  = lds[0][0] + lds[0][1] + lds[0][2] + lds[0][3];
            float swt = lds[1][0] + lds[1][1] + lds[1][2] + lds[1][3];
            atomicAdd(acc + 3, sqrtf(at) * swt);
        }
    } else {
        // ---- entity sim term ----
        const int ri = row_ind[0];
        float a = 0.f;
        for (int i = t; i < JJ * KK; i += 256) {
            int j = i >> 7, k = i & 127;   // consecutive t -> consecutive k (coalesced)
            float x = E[(size_t)ri * KK + k] - E[(size_t)ej[j] * KK + k];
            a = fmaf(x, x, a);
        }
        float se = (t < JJ) ? Se[(size_t)ri * NE + ej[t]] : 0.f;

        #pragma unroll
        for (int off = 32; off > 0; off >>= 1) {
            a += __shfl_down(a, off);
            se += __shfl_down(se, off);
        }
        if (lane == 0) { lds[0][wid] = a; lds[1][wid] = se; }
        __syncthreads();
        if (t == 0) {
            float at = lds[0][0] + lds[0][1] + lds[0][2] + lds[0][3];
            float st = lds[1][0] + lds[1][1] + lds[1][2] + lds[1][3];
            atomicAdd(acc + 3, sqrtf(at) * st);
        }
    }

    // ---- last-block finalize (device-scope ticket; per G16) ----
    __threadfence();
    if (t == 0) {
        unsigned* cnt = (unsigned*)(acc + 4);
        unsigned done = atomicAdd(cnt, 1u);
        if (done == NB_TOT - 1) {
            // atomicAdd(p, 0.f) = device-coherent read (bypasses stale L1/L2)
            float a0 = atomicAdd(acc + 0, 0.f);
            float a1 = atomicAdd(acc + 1, 0.f);
            float a2 = atomicAdd(acc + 2, 0.f);
            float a3 = atomicAdd(acc + 3, 0.f);
            out[0] = sqrtf(a0) + lamb[0] * (sqrtf(a1) + sqrtf(a2)) + a3;
        }
    }
}

extern "C" void kernel_launch(void* const* d_in, const int* in_sizes, int n_in,
                              void* d_out, int out_size, void* d_ws, size_t ws_size,
                              hipStream_t stream) {
    const float* actual     = (const float*)d_in[0];
    const float* prediction = (const float*)d_in[1];
    const float* W          = (const float*)d_in[2];
    const float* E          = (const float*)d_in[3];
    const float* Sw         = (const float*)d_in[4];
    const float* Se         = (const float*)d_in[5];
    const float* lamb       = (const float*)d_in[6];
    const int*   row_ind    = (const int*)d_in[7];
    const int*   wi         = (const int*)d_in[8];
    const int*   ej         = (const int*)d_in[9];
    const int*   sj         = (const int*)d_in[10];

    float* acc = (float*)d_ws;
    hipMemsetAsync(acc, 0, 8 * sizeof(float), stream);  // acc[0..3] + ticket

    k_fused<<<NB_TOT, 256, 0, stream>>>(
        (const float4*)actual, (const float4*)prediction,
        (const float4*)W, (const float4*)E,
        W, E, Sw, Se, row_ind, wi, ej, sj, lamb,
        acc, (float*)d_out);
}

// Round 3
// 934.005 us; speedup vs baseline: 1.0552x; 1.0552x over previous
//
#include <hip/hip_runtime.h>
#include <math.h>

#define NE 4096
#define NW 8192
#define KK 128
#define GG 1024
#define MM 64
#define JJ 256

#define NB_R   2048             // reduction blocks
#define NB_TOT (NB_R + GG + 1)  // + 1024 word-sim blocks + 1 entity block

// ws layout: floats [0..3]=acc, [4]=ticket(uint); Wt (8192x128 f32) at +256 floats

// ---------------------------------------------------------------------------
// Transpose W[128][8192] -> Wt[8192][128] so gathered columns become 512 B
// contiguous rows. 128 blocks x 256 threads, LDS-tiled.
// ---------------------------------------------------------------------------
__global__ __launch_bounds__(256) void k_transpose(const float* __restrict__ W,
                                                   float* __restrict__ Wt) {
    __shared__ float tile[64][KK + 1];   // +1 pad breaks bank aliasing
    const int t = threadIdx.x;
    const int w0 = blockIdx.x * 64;      // 64-wide w-chunk, all 128 k

    // read: lanes sweep w (coalesced 256 B/wave); 4 k-chunks of 32
    const int tw = t & 63, tkc = t >> 6;
    #pragma unroll
    for (int kk = 0; kk < 32; ++kk) {
        int k = tkc * 32 + kk;
        tile[tw][k] = W[(size_t)k * NW + w0 + tw];
    }
    __syncthreads();
    // write: float4 along k (512 B contiguous per row)
    const int tk4 = (t & 31) * 4, trow = t >> 5;
    #pragma unroll
    for (int rr = 0; rr < 8; ++rr) {
        int row = rr * 8 + trow;
        float4 v = make_float4(tile[row][tk4], tile[row][tk4 + 1],
                               tile[row][tk4 + 2], tile[row][tk4 + 3]);
        *(float4*)&Wt[(size_t)(w0 + row) * KK + tk4] = v;
    }
}

// ---------------------------------------------------------------------------
// Fused main kernel.
//  blocks [0, NB_R):       grid-stride reduction (recon, relu(W), relu(E))
//  blocks [NB_R, NB_R+GG): word sim term (reads Wt, coalesced)
//  block  NB_R+GG:         entity sim term
//  last block (ticket) finalizes out[0].
// ---------------------------------------------------------------------------
__global__ __launch_bounds__(256) void k_fused(
    const float4* __restrict__ A, const float4* __restrict__ P,
    const float4* __restrict__ W4, const float4* __restrict__ E4,
    const float* __restrict__ Wt, const float* __restrict__ E,
    const float* __restrict__ Sw, const float* __restrict__ Se,
    const int* __restrict__ row_ind,
    const int* __restrict__ wi, const int* __restrict__ ej,
    const int* __restrict__ sj,
    const float* __restrict__ lamb,
    float* __restrict__ acc, float* __restrict__ out)
{
    __shared__ float lds[3][4];
    __shared__ int wi_s[MM];
    const int b = blockIdx.x;
    const int t = threadIdx.x;
    const int lane = t & 63, wid = t >> 6;

    if (b < NB_R) {
        // ---- big streaming reduction ----
        const size_t RQ = (size_t)NE * NW / 4;
        const size_t WQ = (size_t)KK * NW / 4;
        const size_t EQ = (size_t)NE * KK / 4;
        const size_t TOT = RQ + WQ + EQ;

        float r0 = 0.f, r1 = 0.f, r2 = 0.f;
        const size_t stride = (size_t)NB_R * 256;
        for (size_t i = (size_t)b * 256 + t; i < TOT; i += stride) {
            if (i < RQ) {
                float4 a = A[i];
                float4 p = P[i];
                float dx = a.x - p.x, dy = a.y - p.y, dz = a.z - p.z, dw = a.w - p.w;
                r0 += dx * dx + dy * dy + dz * dz + dw * dw;
            } else if (i < RQ + WQ) {
                float4 w = W4[i - RQ];
                float x = fmaxf(w.x, 0.f), y = fmaxf(w.y, 0.f);
                float z = fmaxf(w.z, 0.f), u = fmaxf(w.w, 0.f);
                r1 += x * x + y * y + z * z + u * u;
            } else {
                float4 e = E4[i - RQ - WQ];
                float x = fmaxf(e.x, 0.f), y = fmaxf(e.y, 0.f);
                float z = fmaxf(e.z, 0.f), u = fmaxf(e.w, 0.f);
                r2 += x * x + y * y + z * z + u * u;
            }
        }
        #pragma unroll
        for (int off = 32; off > 0; off >>= 1) {
            r0 += __shfl_down(r0, off);
            r1 += __shfl_down(r1, off);
            r2 += __shfl_down(r2, off);
        }
        if (lane == 0) { lds[0][wid] = r0; lds[1][wid] = r1; lds[2][wid] = r2; }
        __syncthreads();
        if (t == 0) {
            float s0 = 0.f, s1 = 0.f, s2 = 0.f;
            #pragma unroll
            for (int w = 0; w < 4; ++w) { s0 += lds[0][w]; s1 += lds[1][w]; s2 += lds[2][w]; }
            atomicAdd(acc + 0, s0);
            atomicAdd(acc + 1, s1);
            atomicAdd(acc + 2, s2);
        }
    } else if (b < NB_R + GG) {
        // ---- word sim term: coalesced float4 rows of Wt ----
        const int g = b - NB_R;
        const int sjv = sj[g];
        if (t < MM) wi_s[t] = wi[g * MM + t];
        __syncthreads();

        const int wv = t >> 6;            // wave 0..3: m in [wv*16, wv*16+16)
        const int half = (t & 63) >> 5;   // 2 m's per wave-instruction
        const int kq = (t & 31) * 4;      // lane's k-quad
        const float4 wj = *(const float4*)&Wt[(size_t)sjv * KK + kq];
        float a = 0.f;
        #pragma unroll
        for (int mm = 0; mm < 16; mm += 2) {
            const int m = wv * 16 + mm + half;
            const float4 wv4 = *(const float4*)&Wt[(size_t)wi_s[m] * KK + kq];
            float dx = wv4.x - wj.x, dy = wv4.y - wj.y;
            float dz = wv4.z - wj.z, dw = wv4.w - wj.w;
            a += dx * dx + dy * dy + dz * dz + dw * dw;
        }
        float sw = (t < MM) ? Sw[(size_t)sjv * NW + wi_s[t]] : 0.f;

        #pragma unroll
        for (int off = 32; off > 0; off >>= 1) {
            a += __shfl_down(a, off);
            sw += __shfl_down(sw, off);
        }
        if (lane == 0) { lds[0][wid] = a; lds[1][wid] = sw; }
        __syncthreads();
        if (t == 0) {
            float at  = lds[0][0] + lds[0][1] + lds[0][2] + lds[0][3];
            float swt = lds[1][0] + lds[1][1] + lds[1][2] + lds[1][3];
            atomicAdd(acc + 3, sqrtf(at) * swt);
        }
    } else {
        // ---- entity sim term ----
        const int ri = row_ind[0];
        float a = 0.f;
        for (int i = t; i < JJ * KK; i += 256) {
            int j = i >> 7, k = i & 127;
            float x = E[(size_t)ri * KK + k] - E[(size_t)ej[j] * KK + k];
            a = fmaf(x, x, a);
        }
        float se = (t < JJ) ? Se[(size_t)ri * NE + ej[t]] : 0.f;

        #pragma unroll
        for (int off = 32; off > 0; off >>= 1) {
            a += __shfl_down(a, off);
            se += __shfl_down(se, off);
        }
        if (lane == 0) { lds[0][wid] = a; lds[1][wid] = se; }
        __syncthreads();
        if (t == 0) {
            float at = lds[0][0] + lds[0][1] + lds[0][2] + lds[0][3];
            float st = lds[1][0] + lds[1][1] + lds[1][2] + lds[1][3];
            atomicAdd(acc + 3, sqrtf(at) * st);
        }
    }

    // ---- last-block finalize (device-scope ticket) ----
    __threadfence();
    if (t == 0) {
        unsigned* cnt = (unsigned*)(acc + 4);
        unsigned done = atomicAdd(cnt, 1u);
        if (done == NB_TOT - 1) {
            float a0 = atomicAdd(acc + 0, 0.f);
            float a1 = atomicAdd(acc + 1, 0.f);
            float a2 = atomicAdd(acc + 2, 0.f);
            float a3 = atomicAdd(acc + 3, 0.f);
            out[0] = sqrtf(a0) + lamb[0] * (sqrtf(a1) + sqrtf(a2)) + a3;
        }
    }
}

extern "C" void kernel_launch(void* const* d_in, const int* in_sizes, int n_in,
                              void* d_out, int out_size, void* d_ws, size_t ws_size,
                              hipStream_t stream) {
    const float* actual     = (const float*)d_in[0];
    const float* prediction = (const float*)d_in[1];
    const float* W          = (const float*)d_in[2];
    const float* E          = (const float*)d_in[3];
    const float* Sw         = (const float*)d_in[4];
    const float* Se         = (const float*)d_in[5];
    const float* lamb       = (const float*)d_in[6];
    const int*   row_ind    = (const int*)d_in[7];
    const int*   wi         = (const int*)d_in[8];
    const int*   ej         = (const int*)d_in[9];
    const int*   sj         = (const int*)d_in[10];

    float* ws_f = (float*)d_ws;
    float* acc  = ws_f;            // acc[0..3] + ticket at [4]
    float* Wt   = ws_f + 256;      // 4 MB transposed W, 16B-aligned

    hipMemsetAsync(acc, 0, 8 * sizeof(float), stream);

    k_transpose<<<NW / 64, 256, 0, stream>>>(W, Wt);

    k_fused<<<NB_TOT, 256, 0, stream>>>(
        (const float4*)actual, (const float4*)prediction,
        (const float4*)W, (const float4*)E,
        Wt, E, Sw, Se, row_ind, wi, ej, sj, lamb,
        acc, (float*)d_out);
}